// Round 1
// 257.400 us; speedup vs baseline: 1.0458x; 1.0458x over previous
//
#include <hip/hip_runtime.h>
#include <hip/hip_bf16.h>
#include <stdint.h>

// Problem constants (fixed by reference setup_inputs)
#define T_TOKENS 32768     // 32*1024
#define D_IN     768
#define D_OUT    256
#define N_EXP    8
#define S_TOT    (T_TOKENS*2)   // 65536 routed slots
#define S_PAD    66560          // 65536 + 8*128 worst-case per-expert 128-padding
#define KSPLIT   6              // gate k-split: 768 = 6 x 128
#define NKB      24             // K-blocks of 32 in d_in

typedef __attribute__((ext_vector_type(8))) short bf16x8;
typedef __attribute__((ext_vector_type(4))) float f32x4;

__device__ __forceinline__ unsigned short f2bf(float f) {
    unsigned u = __float_as_uint(f);
    return (unsigned short)((u + 0x7FFFu + ((u >> 16) & 1u)) >> 16);  // RNE
}
__device__ __forceinline__ unsigned pack_bf2(float a, float b) {
    return (unsigned)f2bf(a) | ((unsigned)f2bf(b) << 16);
}

// async global->LDS, 16B per lane. LDS dest must be wave-uniform base + lane*16.
__device__ __forceinline__ void async16(void* lds, const void* g) {
    __builtin_amdgcn_global_load_lds(
        (const __attribute__((address_space(1))) unsigned int*)g,
        (__attribute__((address_space(3))) unsigned int*)lds, 16, 0, 0);
}

// ---- W fp32 [e][k][n] -> bf16 k-blocked [e][kb][n][32kk]; zeroes counts+cursors ----
// Each (e,kb) tile is a contiguous 16 KB slab -> GEMM B staging is fully coalesced.
__global__ __launch_bounds__(256) void convw_kernel(
        const float* __restrict__ W, unsigned short* __restrict__ WTb,
        int* __restrict__ zero16) {
    if (blockIdx.x == 0 && threadIdx.x < 16) zero16[threadIdx.x] = 0;  // counts+cursors
    int eb_ = blockIdx.x;                            // e*NKB + kb, 0..191
    int n = threadIdx.x;
    const float* src = W + ((size_t)(eb_ / NKB) * D_IN + (eb_ % NKB) * 32) * 256 + n;
    unsigned pk[16];
    #pragma unroll
    for (int j = 0; j < 16; j++)                     // reads coalesced (n fastest)
        pk[j] = pack_bf2(src[(2*j) * 256], src[(2*j+1) * 256]);
    unsigned* dst = (unsigned*)(WTb + ((size_t)eb_ * 256 + n) * 32);  // 64 B/thread contig
    #pragma unroll
    for (int j = 0; j < 16; j++) dst[j] = pk[j];
}

// ---- gate stage 1: k-split partial logits. grid=(512,KSPLIT): 64 tokens x 128 k each.
__global__ __launch_bounds__(64) void gate_partial_kernel(
        const float* __restrict__ x, const float* __restrict__ gW,
        unsigned short* __restrict__ xbf, float* __restrict__ partial) {
    __shared__ float tile[64 * 65];
    int tid = threadIdx.x;
    int t0  = blockIdx.x * 64;
    int kq  = blockIdx.y;                            // k-slice 0..KSPLIT-1
    int c16 = tid & 15, rb = tid >> 4;
    float acc[8] = {0,0,0,0,0,0,0,0};
    #pragma unroll 1
    for (int j = 0; j < 2; j++) {
        int kc = kq * 128 + j * 64;
        #pragma unroll
        for (int i = 0; i < 16; i++) {
            int row = i * 4 + rb;
            size_t g = (size_t)(t0 + row) * D_IN + kc + c16 * 4;
            float4 v = *(const float4*)(x + g);
            uint2 p; p.x = pack_bf2(v.x, v.y); p.y = pack_bf2(v.z, v.w);
            *(uint2*)(xbf + g) = p;                  // fused bf16 emit (coalesced 8B)
            float* d = &tile[row * 65 + c16 * 4];
            d[0] = v.x; d[1] = v.y; d[2] = v.z; d[3] = v.w;  // ~2-way banks: free
        }
        __syncthreads();
        const float* gr = gW + (size_t)kc * 8;       // wave-uniform -> s_load
        #pragma unroll 8
        for (int kk = 0; kk < 64; kk++) {
            float xv = tile[tid * 65 + kk];          // bank (l+kk)%32: conflict-free
            #pragma unroll
            for (int e = 0; e < 8; e++) acc[e] += xv * gr[kk * 8 + e];
        }
        __syncthreads();
    }
    float* dst = partial + ((size_t)kq * T_TOKENS + t0 + tid) * 8;
    float4 o0 = {acc[0], acc[1], acc[2], acc[3]};
    float4 o1 = {acc[4], acc[5], acc[6], acc[7]};
    *(float4*)dst = o0; *(float4*)(dst + 4) = o1;    // 32B/token, coalesced
}

// ---- gate stage 2: sum partials (FIXED order: deterministic), softmax, top-2, hist ----
__global__ __launch_bounds__(256) void gate_final_kernel(
        const float* __restrict__ partial, const float* __restrict__ gb,
        float* __restrict__ topk_w, int* __restrict__ topk_e, int* __restrict__ counts) {
    __shared__ int h[8];
    int tid = threadIdx.x;
    if (tid < 8) h[tid] = 0;
    __syncthreads();
    int t = blockIdx.x * 256 + tid;
    float acc[8] = {0,0,0,0,0,0,0,0};
    #pragma unroll
    for (int q = 0; q < KSPLIT; q++) {               // fixed summation order
        const float* p = partial + ((size_t)q * T_TOKENS + t) * 8;
        float4 a = *(const float4*)p;
        float4 b = *(const float4*)(p + 4);
        acc[0] += a.x; acc[1] += a.y; acc[2] += a.z; acc[3] += a.w;
        acc[4] += b.x; acc[5] += b.y; acc[6] += b.z; acc[7] += b.w;
    }
    float mx = -1e30f;
    #pragma unroll
    for (int e = 0; e < 8; e++) { acc[e] += gb[e]; mx = fmaxf(mx, acc[e]); }
    float w[8], s = 0.f;
    #pragma unroll
    for (int e = 0; e < 8; e++) { w[e] = expf(acc[e] - mx); s += w[e]; }
    float inv = 1.0f / s;
    int e0 = 0; float b0 = -1.f;
    #pragma unroll
    for (int e = 0; e < 8; e++) if (w[e] > b0) { b0 = w[e]; e0 = e; }   // ties -> lowest idx
    int e1 = 0; float b1 = -1.f;
    #pragma unroll
    for (int e = 0; e < 8; e++) if (e != e0 && w[e] > b1) { b1 = w[e]; e1 = e; }
    topk_w[t*2]   = b0 * inv;
    topk_w[t*2+1] = b1 * inv;
    topk_e[t*2]   = e0;
    topk_e[t*2+1] = e1;
    atomicAdd(&h[e0], 1); atomicAdd(&h[e1], 1);
    __syncthreads();
    if (tid < 8) atomicAdd(&counts[tid], h[tid]);
}

// ---- scatter (token,w) into expert buckets + inverse map; 128-aligned regions ----
__global__ void scatter_kernel(const int* __restrict__ topk_e, const float* __restrict__ topk_w,
                               const int* __restrict__ counts, int* __restrict__ cursors,
                               int* __restrict__ slot_token, float* __restrict__ slot_w,
                               int* __restrict__ inv_slot) {
    int offs[9]; offs[0] = 0;
    #pragma unroll
    for (int e = 0; e < 8; e++) offs[e+1] = offs[e] + ((counts[e] + 127) & ~127);
    __shared__ int hcnt[8], hbase[8];
    if (threadIdx.x < 8) hcnt[threadIdx.x] = 0;
    __syncthreads();
    int idx[4], ee[4], lr[4];
    int base = blockIdx.x * 256 * 4 + threadIdx.x;
    #pragma unroll
    for (int j = 0; j < 4; j++) {
        idx[j] = base + j * 256;
        ee[j]  = topk_e[idx[j]];
        lr[j]  = atomicAdd(&hcnt[ee[j]], 1);
    }
    __syncthreads();
    if (threadIdx.x < 8) hbase[threadIdx.x] = atomicAdd(&cursors[threadIdx.x], hcnt[threadIdx.x]);
    __syncthreads();
    #pragma unroll
    for (int j = 0; j < 4; j++) {
        int slot = offs[ee[j]] + hbase[ee[j]] + lr[j];
        slot_token[slot] = idx[j] >> 1;
        slot_w[slot]     = topk_w[idx[j]];
        inv_slot[idx[j]] = slot;
    }
}

// ---- routed GEMM: 128 slots x 256 cols/block, BK=32, 3-stage pipeline, raw barriers ----
// R6 change: 512 threads (8 waves, 2Mx4N) for the SAME 128x256 tile. LDS stays 72 KB
// -> 2 blocks/CU -> 16 waves/CU (4/SIMD) vs the old 8. Per-wave work halves
// (16 MFMA + 8 ds_read/step, 3 VMEM/stage -> vmcnt(3)); the counted-vmcnt distance-2
// pipeline is unchanged. Rationale: counters showed MfmaUtil 12 / VALUBusy 7 /
// Occupancy 13.5 / HBM 20% — pure latency-bound; TLP is the missing resource.
// Also: bijective XCD-chunked swizzle (520 = 8*65) so same-expert blocks share an
// XCD L2 (B panel = 384 KB), and s_setprio(1) around the MFMA cluster (T5).
template<bool ROUTED>
__global__ __launch_bounds__(512, 4) void moe_gemm_kernel(
        const unsigned short* __restrict__ xbf, const unsigned short* __restrict__ WTb,
        const float* __restrict__ eb, const int* __restrict__ counts,
        const int* __restrict__ slot_token, const float* __restrict__ slot_w,
        float* __restrict__ dst) {
    __shared__ unsigned short A_lds[3][128 * 32];    // 3 x 8 KB
    __shared__ unsigned short B_lds[3][256 * 32];    // 3 x 16 KB  -> 72 KB total

    // XCD-chunked swizzle: hw round-robins blockIdx across 8 XCDs; remap so XCD x
    // runs logical blocks [x*65, (x+1)*65) = contiguous slot range (<=2 experts).
    int lbid = (blockIdx.x & 7) * ((int)gridDim.x >> 3) + (blockIdx.x >> 3);

    int offs[9]; offs[0] = 0;
    #pragma unroll
    for (int e = 0; e < 8; e++) offs[e+1] = offs[e] + ((counts[e] + 127) & ~127);
    int row0 = lbid * 128;
    if (row0 >= offs[8]) return;                     // uniform exit
    int expert = 0;
    #pragma unroll
    for (int e = 0; e < 8; e++) if (row0 >= offs[e]) expert = e;

    int tid  = threadIdx.x;
    int wave = tid >> 6, lane = tid & 63;
    int lrow = lane & 15, lquad = lane >> 4;
    int wm = wave >> 2, wn = wave & 3;               // 2 (M) x 4 (N) wave grid

    // ---- staging sources (LDS dest linear-by-thread; chunk-rotate the SOURCE) ----
    // A: 512 16B-chunks (128 rows x 4) = 1 chunk/thread; gathered rows (row-major xbf)
    int ar = tid >> 2, ap = tid & 3;
    int alc = (ap - (ar >> 1)) & 3;                  // logical chunk at this phys slot
    int tok = slot_token[row0 + ar];
    tok = (tok < 0 || tok >= T_TOKENS) ? 0 : tok;    // pad slots hold poison: clamp
    const unsigned short* asrc = xbf + (size_t)tok * D_IN + alc * 8;

    // B: k-blocked tile = contiguous 16 KB; 2 chunks/thread, offset within tile fixed
    const unsigned short* bexp = WTb + (size_t)expert * NKB * 8192;
    int boff[2];
    #pragma unroll
    for (int i = 0; i < 2; i++) {
        int c = i * 512 + tid;
        int r = c >> 2, p = c & 3;
        int lc = (p - (r >> 1)) & 3;
        boff[i] = r * 32 + lc * 8;                   // shorts within 16 KB tile
    }

    // frag LDS offsets (shorts), constant across K
    int a_off[4], b_off[4];
    #pragma unroll
    for (int m = 0; m < 4; m++) {
        int r = wm * 64 + m * 16 + lrow;
        a_off[m] = r * 32 + ((lquad + (r >> 1)) & 3) * 8;
    }
    #pragma unroll
    for (int q = 0; q < 4; q++) {
        int r = wn * 64 + q * 16 + lrow;
        b_off[q] = r * 32 + ((lquad + (r >> 1)) & 3) * 8;
    }

    f32x4 acc[4][4];
    #pragma unroll
    for (int m = 0; m < 4; m++)
        #pragma unroll
        for (int q = 0; q < 4; q++) acc[m][q] = (f32x4){0,0,0,0};

    auto stage = [&](int kb, int st) {               // 3 VMEM instrs per wave
        async16(&A_lds[st][tid * 8], asrc + kb * 32);
        const unsigned short* tb = bexp + (size_t)kb * 8192;
        #pragma unroll
        for (int i = 0; i < 2; i++)
            async16(&B_lds[st][(i * 512 + tid) * 8], tb + boff[i]);
    };

    stage(0, 0);
    stage(1, 1);
    for (int s = 0; s < NKB; s++) {
        // wait: oldest in-flight stage (s) done; stage(s+1) may stay in flight
        if (s == NKB - 1) asm volatile("s_waitcnt vmcnt(0)" ::: "memory");
        else              asm volatile("s_waitcnt vmcnt(3)" ::: "memory");
        asm volatile("s_barrier" ::: "memory");      // raw: no compiler vmcnt(0) drain
        if (s + 2 < NKB) stage(s + 2, (s + 2) % 3);
        int p = s % 3;
        bf16x8 a[4], b[4];
        #pragma unroll
        for (int m = 0; m < 4; m++) a[m] = *(const bf16x8*)&A_lds[p][a_off[m]];
        #pragma unroll
        for (int q = 0; q < 4; q++) b[q] = *(const bf16x8*)&B_lds[p][b_off[q]];
        __builtin_amdgcn_s_setprio(1);
        #pragma unroll
        for (int q = 0; q < 4; q++)
            #pragma unroll
            for (int m = 0; m < 4; m++)
                acc[m][q] = __builtin_amdgcn_mfma_f32_16x16x32_bf16(a[m], b[q], acc[m][q], 0, 0, 0);
        __builtin_amdgcn_s_setprio(0);
    }

    // epilogue: D mapping col=lane&15, row=quad*4+reg
    float bias_q[4];
    #pragma unroll
    for (int q = 0; q < 4; q++) bias_q[q] = eb[expert * D_OUT + wn * 64 + q * 16 + lrow];
    #pragma unroll
    for (int m = 0; m < 4; m++) {
        #pragma unroll
        for (int r = 0; r < 4; r++) {
            int slot = row0 + wm * 64 + m * 16 + lquad * 4 + r;
            if constexpr (ROUTED) {
                float* drow = dst + (size_t)slot * D_OUT + wn * 64;
                #pragma unroll
                for (int q = 0; q < 4; q++)
                    drow[q * 16 + lrow] = acc[m][q][r] + bias_q[q];
            } else {
                int tk = slot_token[slot];
                float wgt = slot_w[slot];            // pads have wgt=0 (memset in this path)
                #pragma unroll
                for (int q = 0; q < 4; q++)
                    atomicAdd(dst + (size_t)tk * D_OUT + wn * 64 + q * 16 + lrow,
                              wgt * (acc[m][q][r] + bias_q[q]));
            }
        }
    }
}

// ---------------- combine: out[t] = w0*routed[s0] + w1*routed[s1] ----------------
__global__ void combine_kernel(const float* __restrict__ routed, const int* __restrict__ inv_slot,
                               const float* __restrict__ topk_w, float* __restrict__ out) {
    int flat = blockIdx.x * 256 + threadIdx.x;       // float4 index
    int t = flat >> 6, c = (flat & 63) * 4;
    int   s0 = inv_slot[t*2], s1 = inv_slot[t*2+1];
    float w0 = topk_w[t*2],   w1 = topk_w[t*2+1];
    float4 r0 = *(const float4*)(routed + (size_t)s0 * D_OUT + c);
    float4 r1 = *(const float4*)(routed + (size_t)s1 * D_OUT + c);
    float4 o;
    o.x = w0*r0.x + w1*r1.x; o.y = w0*r0.y + w1*r1.y;
    o.z = w0*r0.z + w1*r1.z; o.w = w0*r0.w + w1*r1.w;
    *(float4*)(out + (size_t)t * D_OUT + c) = o;
}

extern "C" void kernel_launch(void* const* d_in, const int* in_sizes, int n_in,
                              void* d_out, int out_size, void* d_ws, size_t ws_size,
                              hipStream_t stream) {
    const float* x  = (const float*)d_in[0];
    const float* gW = (const float*)d_in[1];
    const float* gb = (const float*)d_in[2];
    const float* eW = (const float*)d_in[3];
    const float* eb = (const float*)d_in[4];
    float* out = (float*)d_out;
    char* ws = (char*)d_ws;

    // ws layout
    float* topk_w      = (float*)(ws + 0);                 // 256 KB
    int*   topk_e      = (int*)  (ws + 262144);            // 256 KB
    int*   counts      = (int*)  (ws + 524288);            // 8 ints
    int*   cursors     = (int*)  (ws + 524320);            // 8 ints  (contiguous w/ counts)
    int*   slot_token  = (int*)  (ws + 524416);            // 266240 B (S_PAD)
    float* slot_w      = (float*)(ws + 790656);            // 266240 B (S_PAD)
    int*   inv_slot    = (int*)  (ws + 1056896);           // 262144 B (S_TOT)
    float* partial     = (float*)(ws + 1319040);           // 6 MB  [KSPLIT][T][8] fp32
    unsigned short* WTb= (unsigned short*)(ws + 7610496);  // 3 MB bf16 W k-blocked
    unsigned short* xbf= (unsigned short*)(ws + 10756224); // 48 MB bf16 x
    float* routed      = (float*)(ws + 61087872);          // 68 MB routed outputs
    const size_t NEED_ROUTED = 61087872 + (size_t)S_PAD * D_OUT * 4;  // ~129 MB
    bool use_routed = (ws_size >= NEED_ROUTED);

    convw_kernel       <<<N_EXP * NKB, 256, 0, stream>>>(eW, WTb, counts);
    gate_partial_kernel<<<dim3(T_TOKENS / 64, KSPLIT), 64, 0, stream>>>(x, gW, xbf, partial);
    gate_final_kernel  <<<T_TOKENS / 256, 256, 0, stream>>>(partial, gb, topk_w, topk_e, counts);
    scatter_kernel     <<<S_TOT / (256 * 4), 256, 0, stream>>>(topk_e, topk_w, counts, cursors,
                                                               slot_token, slot_w, inv_slot);
    if (use_routed) {
        moe_gemm_kernel<true><<<S_PAD / 128, 512, 0, stream>>>(xbf, WTb, eb, counts,
                                                               slot_token, slot_w, routed);
        combine_kernel<<<T_TOKENS * D_OUT / 4 / 256, 256, 0, stream>>>(routed, inv_slot,
                                                                       topk_w, out);
    } else {
        // fallback: pads must be (token=0, w=0) for the atomic path
        hipMemsetAsync(slot_token, 0, 532480, stream);
        hipMemsetAsync(out, 0, (size_t)out_size * sizeof(float), stream);
        moe_gemm_kernel<false><<<S_PAD / 128, 512, 0, stream>>>(xbf, WTb, eb, counts,
                                                                slot_token, slot_w, out);
    }
}